// Round 9
// baseline (179.124 us; speedup 1.0000x reference)
//
#include <hip/hip_runtime.h>
#include <hip/hip_bf16.h>
#include <stdint.h>

typedef __attribute__((ext_vector_type(8))) short short8;
typedef __attribute__((ext_vector_type(16))) float f32x16;

#define BIGF 1e9f
#define NSLOT 16                 // 4 splits x 4 wc groups
#define MAXM 96                  // max genuine members per pid (λ≈16, safe)

__device__ inline float blo(unsigned int u) {
    union { unsigned int i; float f; } v; v.i = u << 16; return v.f;
}
__device__ inline float bhi(unsigned int u) {
    union { unsigned int i; float f; } v; v.i = u & 0xffff0000u; return v.f;
}
__device__ inline unsigned int fkey(float s) {   // order-preserving uint encode
    unsigned int b = __float_as_uint(s);
    return (b & 0x80000000u) ? ~b : (b | 0x80000000u);
}
__device__ inline float funkey(unsigned int k) {
    unsigned int b = (k & 0x80000000u) ? (k & 0x7fffffffu) : ~k;
    return __uint_as_float(b);
}
__device__ inline void async16(const unsigned short* g, unsigned short* l) {
    __builtin_amdgcn_global_load_lds(
        (const __attribute__((address_space(1))) void*)g,
        (__attribute__((address_space(3))) void*)l, 16, 0, 0);
}
__device__ inline unsigned short f2b(float x) {
    __hip_bfloat16 h = __float2bfloat16(x);
    return *reinterpret_cast<unsigned short*>(&h);
}

// ---------------------------------------------------------------------------
// Kernel 1 (fused prep): blocks [0, N/4): normalize 4 rows -> bf16 normed +
// gpid; hp=BIGF for non-genuine rows; block 0 zeroes gred/done.
// Blocks [N/4, N/4+256): hardest positive for one pid (members normalized
// from raw emb with identical bf16 rounding; M^2 LDS dots).
// ---------------------------------------------------------------------------
__global__ __launch_bounds__(256) void k_prep(
    const float* __restrict__ emb, const int* __restrict__ labels,
    const int* __restrict__ pids, unsigned short* __restrict__ normed,
    int* __restrict__ gpid, float* __restrict__ hp_out,
    float* __restrict__ gred, int* __restrict__ done, int N)
{
    __shared__ int list[MAXM];
    __shared__ unsigned int hp_loc[MAXM];
    __shared__ unsigned short rows[MAXM * 256];   // 48 KB
    __shared__ int cnt;

    const int b = blockIdx.x;
    const int t = threadIdx.x;
    const int nblk = N / 4;
    const int w = t >> 6, lane = t & 63;

    if (b < nblk) {
        if (b == 0 && t < 3) {
            if (t < 2) gred[t] = 0.f;
            else *done = 0;
        }
        int row = b * 4 + w;
        const float4* src = (const float4*)(emb + ((size_t)row << 8));
        float4 x = src[lane];
        float ss = x.x * x.x + x.y * x.y + x.z * x.z + x.w * x.w;
        #pragma unroll
        for (int off = 32; off >= 1; off >>= 1) ss += __shfl_xor(ss, off, 64);
        float inv = 1.0f / fmaxf(sqrtf(ss), 1e-12f);
        ushort4 o;
        o.x = f2b(x.x * inv); o.y = f2b(x.y * inv);
        o.z = f2b(x.z * inv); o.w = f2b(x.w * inv);
        ((ushort4*)(normed + ((size_t)row << 8)))[lane] = o;
        if (lane == 0) {
            int genuine = (labels[row] == 1);
            gpid[row] = genuine ? pids[row] : -1;
            if (!genuine) hp_out[row] = BIGF;
        }
        return;
    }

    int p = b - nblk;
    if (t == 0) cnt = 0;
    __syncthreads();
    for (int j = t; j < N; j += 256)
        if (pids[j] == p && labels[j] == 1) {
            int idx = atomicAdd(&cnt, 1);
            if (idx < MAXM) list[idx] = j;
        }
    __syncthreads();
    int M = min(cnt, MAXM);
    for (int s = t; s < M; s += 256) hp_loc[s] = 0xFFFFFFFFu;
    for (int mi = w; mi < M; mi += 4) {
        const float4* src = (const float4*)(emb + ((size_t)list[mi] << 8));
        float4 x = src[lane];
        float ss = x.x * x.x + x.y * x.y + x.z * x.z + x.w * x.w;
        #pragma unroll
        for (int off = 32; off >= 1; off >>= 1) ss += __shfl_xor(ss, off, 64);
        float inv = 1.0f / fmaxf(sqrtf(ss), 1e-12f);
        ushort4 o;
        o.x = f2b(x.x * inv); o.y = f2b(x.y * inv);
        o.z = f2b(x.z * inv); o.w = f2b(x.w * inv);
        ((ushort4*)&rows[mi * 256])[lane] = o;
    }
    __syncthreads();
    for (int pr = t; pr < M * M; pr += 256) {
        int i = pr / M, j = pr - i * M;
        if (i == j) continue;
        const uint4* ap = (const uint4*)&rows[i * 256];
        const uint4* bp = (const uint4*)&rows[j * 256];
        float s = 0.f;
        #pragma unroll 4
        for (int k = 0; k < 32; ++k) {
            uint4 a = ap[k], bb = bp[k];
            s += blo(a.x) * blo(bb.x) + bhi(a.x) * bhi(bb.x);
            s += blo(a.y) * blo(bb.y) + bhi(a.y) * bhi(bb.y);
            s += blo(a.z) * blo(bb.z) + bhi(a.z) * bhi(bb.z);
            s += blo(a.w) * blo(bb.w) + bhi(a.w) * bhi(bb.w);
        }
        atomicMin(&hp_loc[i], fkey(s));
    }
    __syncthreads();
    for (int s = t; s < M; s += 256) {
        unsigned int key = hp_loc[s];
        hp_out[list[s]] = (key == 0xFFFFFFFFu) ? BIGF : funkey(key);
    }
}

// ---------------------------------------------------------------------------
// Kernel 2: persistent MFMA pass with 32x32x16 (halved LDS bytes/FLOP vs
// 16x16x32 -- R8 was LDS-read-bound at ~85 B/cyc). Grid = 64 strips x 4
// splits = 256 blocks (1/CU). 512 thr = 8 waves (wr 2 x wc 4), wave tile
// 64x64 (mt=2, nt=2, 16-reg acc each). A-tile 128x256 (64 KB) staged once,
// XOR-swizzled 16B chunks (p = c ^ (row&7)); B 8 KB/step double-buffered.
// Per step: 32 ds_read_b128 (32 KB) vs 310 cyc MFMA -> MFMA-bound.
// A/B operand layout: elem j of short8 = k = kb*16 + (lane>>5)*8 + j,
// A row / B col = lane&31. C/D: col=lane&31, row=(reg&3)+8*(reg>>2)+
// 4*(lane>>5)  [measured m74/m101].
// ---------------------------------------------------------------------------
__global__ __launch_bounds__(512, 2) void k_pass2(
    const unsigned short* __restrict__ normed, const int* __restrict__ pids,
    const int* __restrict__ gpid, const float* __restrict__ hp,
    float* __restrict__ p_hn, float* __restrict__ p_mb, int N)
{
    __shared__ unsigned short Afull[128 * 32 * 8];   // 64 KB
    __shared__ unsigned short Bs[2][512 * 8];        // 2 x 8 KB
    __shared__ int pid_s[128];
    __shared__ float hp_s[128];

    const int t = threadIdx.x;
    const int lane = t & 63;
    const int w = t >> 6;
    const int wr = w & 1, wc = w >> 1;       // 2 row groups x 4 col groups
    const int l32 = lane & 31, lhi = lane >> 5;
    const int strip = blockIdx.x >> 2;       // 64 strips of 128 rows
    const int split = blockIdx.x & 3;
    const int rbase = strip * 128;
    const int colspan = N >> 2;              // 2048
    const int cstart = split * colspan;

    if (t < 128) { pid_s[t] = pids[rbase + t]; hp_s[t] = hp[rbase + t]; }

    // ---- A prologue: 128 rows x 32 chunks (16B), swizzle p = c ^ (row&7) --
    #pragma unroll
    for (int i = 0; i < 8; ++i) {
        int L = i * 512 + t;
        int row = L >> 5, pos = L & 31;
        int c = (pos & 24) | ((pos ^ row) & 7);
        async16(normed + ((size_t)(rbase + row) << 8) + c * 8, &Afull[L * 8]);
    }
    // ---- B step-0 prefetch: chunk t = (h=t>>8)*256 + (j=t&255) ----
    const int bj = t & 255, bh = t >> 8;
    const unsigned short* gBp = normed + ((size_t)(cstart + bj) << 8) + bh * 8;
    async16(gBp, &Bs[0][t * 8]);

    __syncthreads();   // drain A + B0; pid_s/hp_s visible

    // register caches: rows rl = wr*64 + mt*32 + lhi*4 + (reg&3) + 8*(reg>>2)
    int pid_c[2][16]; float hp_c[2][16];
    float hnall[2][16], mbel[2][16];
    f32x16 acc[2][2];
    #pragma unroll
    for (int mt = 0; mt < 2; ++mt)
        #pragma unroll
        for (int reg = 0; reg < 16; ++reg) {
            int rl = wr * 64 + mt * 32 + lhi * 4 + (reg & 3) + 8 * (reg >> 2);
            pid_c[mt][reg] = pid_s[rl];
            hp_c[mt][reg] = hp_s[rl];
            hnall[mt][reg] = -BIGF;
            mbel[mt][reg] = -BIGF;
            acc[mt][0][reg] = 0.f;
            acc[mt][1][reg] = 0.f;
        }

    int gpn[2];
    int buf = 0;
    for (int s = 0; s < 128; ++s) {
        const int ti = s >> 4, kb = s & 15;
        if (s < 127) {
            int s1 = s + 1;
            async16(gBp + ((size_t)(s1 >> 4) << 16) + (s1 & 15) * 16,
                    &Bs[buf ^ 1][t * 8]);
        }
        if (kb == 0) {
            int cb = cstart + ti * 256;
            gpn[0] = gpid[cb + wc * 64 + l32];
            gpn[1] = gpid[cb + wc * 64 + 32 + l32];
        }
        short8 af[2], bf[2];
        #pragma unroll
        for (int mt = 0; mt < 2; ++mt) {
            int R = wr * 64 + mt * 32 + l32;
            int cw = kb * 2 + lhi;
            int p = (cw & 24) | ((cw ^ R) & 7);
            af[mt] = *reinterpret_cast<const short8*>(&Afull[(R * 32 + p) * 8]);
        }
        #pragma unroll
        for (int nt = 0; nt < 2; ++nt)
            bf[nt] = *reinterpret_cast<const short8*>(
                &Bs[buf][(lhi * 256 + wc * 64 + nt * 32 + l32) * 8]);
        #pragma unroll
        for (int mt = 0; mt < 2; ++mt)
            #pragma unroll
            for (int nt = 0; nt < 2; ++nt)
                acc[mt][nt] = __builtin_amdgcn_mfma_f32_32x32x16_bf16(
                    af[mt], bf[nt], acc[mt][nt], 0, 0, 0);
        if (kb == 15) {
            // per-tile epilogue (VALU; co-schedules with other waves' MFMA)
            #pragma unroll
            for (int nt = 0; nt < 2; ++nt) {
                int gp = gpn[nt];
                #pragma unroll
                for (int mt = 0; mt < 2; ++mt)
                    #pragma unroll
                    for (int reg = 0; reg < 16; ++reg) {
                        float sv = acc[mt][nt][reg];
                        float tt = (pid_c[mt][reg] != gp) ? sv : -BIGF;
                        hnall[mt][reg] = fmaxf(hnall[mt][reg], tt);
                        float u = (tt < hp_c[mt][reg]) ? tt : -BIGF;
                        mbel[mt][reg] = fmaxf(mbel[mt][reg], u);
                        acc[mt][nt][reg] = 0.f;
                    }
            }
        }
        buf ^= 1;
        __syncthreads();
    }

    // block epilogue: reduce across the 32 col-lanes (stays within lhi half)
    #pragma unroll
    for (int mt = 0; mt < 2; ++mt)
        #pragma unroll
        for (int reg = 0; reg < 16; ++reg) {
            float v1 = hnall[mt][reg], v2 = mbel[mt][reg];
            #pragma unroll
            for (int off = 16; off >= 1; off >>= 1) {
                v1 = fmaxf(v1, __shfl_xor(v1, off, 64));
                v2 = fmaxf(v2, __shfl_xor(v2, off, 64));
            }
            if (l32 == 0) {
                int row = rbase + wr * 64 + mt * 32 + lhi * 4
                        + (reg & 3) + 8 * (reg >> 2);
                int slot = split * 4 + wc;
                p_hn[(size_t)slot * N + row] = v1;
                p_mb[(size_t)slot * N + row] = v2;
            }
        }
}

// ---------------------------------------------------------------------------
// Kernel 3: per-row loss + grid reduce + fused final (last-block pattern).
// hn = (mbel > hp - margin) ? mbel : hn_all   (hn_cand == hn_all identity)
// ---------------------------------------------------------------------------
__global__ __launch_bounds__(256) void k_rowloss(
    const float* __restrict__ hp, const float* __restrict__ p_hn,
    const float* __restrict__ p_mb, const int* __restrict__ labels,
    float* __restrict__ gred, int* __restrict__ done,
    float* __restrict__ out, int N)
{
    int i = blockIdx.x * 256 + threadIdx.x;
    float hn_all = -BIGF, mb = -BIGF;
    #pragma unroll
    for (int s = 0; s < NSLOT; ++s) {
        hn_all = fmaxf(hn_all, p_hn[(size_t)s * N + i]);
        mb = fmaxf(mb, p_mb[(size_t)s * N + i]);
    }
    float hpv = hp[i];
    bool valid = (labels[i] == 1) && (hpv < 1e8f) && (hn_all > -1e8f);
    float hn = (mb > hpv - 0.5f) ? mb : hn_all;
    float base = fmaxf(hn - hpv + 0.5f, 0.f);
    float wgt = (hpv < 0.6f || hn > 0.3f) ? 2.f : 1.f;
    float loss = base * wgt + 0.5f * (1.f - hpv) + 0.5f * fmaxf(hn + 0.2f, 0.f);
    float lsum = valid ? loss : 0.f;
    float lcnt = valid ? 1.f : 0.f;
    #pragma unroll
    for (int off = 32; off >= 1; off >>= 1) {
        lsum += __shfl_xor(lsum, off, 64);
        lcnt += __shfl_xor(lcnt, off, 64);
    }
    __shared__ float rs[4], rc[4];
    int wv = threadIdx.x >> 6, lane = threadIdx.x & 63;
    if (lane == 0) { rs[wv] = lsum; rc[wv] = lcnt; }
    __syncthreads();
    if (threadIdx.x == 0) {
        atomicAdd(&gred[0], rs[0] + rs[1] + rs[2] + rs[3]);
        atomicAdd(&gred[1], rc[0] + rc[1] + rc[2] + rc[3]);
        __threadfence();
        int old = atomicAdd(done, 1);
        if (old == (int)gridDim.x - 1) {
            float S = atomicAdd(&gred[0], 0.f);
            float C = atomicAdd(&gred[1], 0.f);
            out[0] = (C > 0.f) ? S / fmaxf(C, 1.f) : 0.f;
        }
    }
}

extern "C" void kernel_launch(void* const* d_in, const int* in_sizes, int n_in,
                              void* d_out, int out_size, void* d_ws, size_t ws_size,
                              hipStream_t stream)
{
    const float* emb = (const float*)d_in[0];
    const int* labels = (const int*)d_in[1];
    const int* pids = (const int*)d_in[2];
    float* out = (float*)d_out;
    int N = in_sizes[1];          // 8192

    char* ws = (char*)d_ws;
    unsigned short* normed = (unsigned short*)ws;  ws += (size_t)N * 256 * 2;  // 4 MB
    int* gpid = (int*)ws;                          ws += (size_t)N * 4;
    float* hp = (float*)ws;                        ws += (size_t)N * 4;
    float* p_hn = (float*)ws;                      ws += (size_t)N * NSLOT * 4;
    float* p_mb = (float*)ws;                      ws += (size_t)N * NSLOT * 4;
    float* gred = (float*)ws;                      ws += 2 * 4;
    int* done = (int*)ws;                          ws += 4;

    k_prep<<<N / 4 + 256, 256, 0, stream>>>(emb, labels, pids, normed, gpid,
                                            hp, gred, done, N);
    k_pass2<<<(N / 128) * 4, 512, 0, stream>>>(normed, pids, gpid, hp,
                                               p_hn, p_mb, N);
    k_rowloss<<<N / 256, 256, 0, stream>>>(hp, p_hn, p_mb, labels,
                                           gred, done, out, N);
}

// Round 10
// 150.170 us; speedup vs baseline: 1.1928x; 1.1928x over previous
//
#include <hip/hip_runtime.h>
#include <hip/hip_bf16.h>
#include <stdint.h>

typedef __attribute__((ext_vector_type(8))) short short8;
typedef __attribute__((ext_vector_type(4))) float f32x4;

#define BIGF 1e9f
#define NSLOT 16                 // 4 splits x 4 wc groups
#define MAXM 96                  // max genuine members per pid (λ≈16, safe)

__device__ inline float blo(unsigned int u) {
    union { unsigned int i; float f; } v; v.i = u << 16; return v.f;
}
__device__ inline float bhi(unsigned int u) {
    union { unsigned int i; float f; } v; v.i = u & 0xffff0000u; return v.f;
}
__device__ inline unsigned int fkey(float s) {   // order-preserving uint encode
    unsigned int b = __float_as_uint(s);
    return (b & 0x80000000u) ? ~b : (b | 0x80000000u);
}
__device__ inline float funkey(unsigned int k) {
    unsigned int b = (k & 0x80000000u) ? (k & 0x7fffffffu) : ~k;
    return __uint_as_float(b);
}
__device__ inline void async16(const unsigned short* g, unsigned short* l) {
    __builtin_amdgcn_global_load_lds(
        (const __attribute__((address_space(1))) void*)g,
        (__attribute__((address_space(3))) void*)l, 16, 0, 0);
}
__device__ inline unsigned short f2b(float x) {
    __hip_bfloat16 h = __float2bfloat16(x);
    return *reinterpret_cast<unsigned short*>(&h);
}

// ---------------------------------------------------------------------------
// Kernel 1 (fused prep): blocks [0, N/4): normalize 4 rows -> bf16 normed +
// gpid; hp=BIGF for non-genuine rows; block 0 zeroes gred/done.
// Blocks [N/4, N/4+256): hardest positive for one pid (members normalized
// from raw emb with identical bf16 rounding; M^2 LDS dots).
// ---------------------------------------------------------------------------
__global__ __launch_bounds__(256) void k_prep(
    const float* __restrict__ emb, const int* __restrict__ labels,
    const int* __restrict__ pids, unsigned short* __restrict__ normed,
    int* __restrict__ gpid, float* __restrict__ hp_out,
    float* __restrict__ gred, int* __restrict__ done, int N)
{
    __shared__ int list[MAXM];
    __shared__ unsigned int hp_loc[MAXM];
    __shared__ unsigned short rows[MAXM * 256];   // 48 KB
    __shared__ int cnt;

    const int b = blockIdx.x;
    const int t = threadIdx.x;
    const int nblk = N / 4;
    const int w = t >> 6, lane = t & 63;

    if (b < nblk) {
        if (b == 0 && t < 3) {
            if (t < 2) gred[t] = 0.f;
            else *done = 0;
        }
        int row = b * 4 + w;
        const float4* src = (const float4*)(emb + ((size_t)row << 8));
        float4 x = src[lane];
        float ss = x.x * x.x + x.y * x.y + x.z * x.z + x.w * x.w;
        #pragma unroll
        for (int off = 32; off >= 1; off >>= 1) ss += __shfl_xor(ss, off, 64);
        float inv = 1.0f / fmaxf(sqrtf(ss), 1e-12f);
        ushort4 o;
        o.x = f2b(x.x * inv); o.y = f2b(x.y * inv);
        o.z = f2b(x.z * inv); o.w = f2b(x.w * inv);
        ((ushort4*)(normed + ((size_t)row << 8)))[lane] = o;
        if (lane == 0) {
            int genuine = (labels[row] == 1);
            gpid[row] = genuine ? pids[row] : -1;
            if (!genuine) hp_out[row] = BIGF;
        }
        return;
    }

    int p = b - nblk;
    if (t == 0) cnt = 0;
    __syncthreads();
    for (int j = t; j < N; j += 256)
        if (pids[j] == p && labels[j] == 1) {
            int idx = atomicAdd(&cnt, 1);
            if (idx < MAXM) list[idx] = j;
        }
    __syncthreads();
    int M = min(cnt, MAXM);
    for (int s = t; s < M; s += 256) hp_loc[s] = 0xFFFFFFFFu;
    for (int mi = w; mi < M; mi += 4) {
        const float4* src = (const float4*)(emb + ((size_t)list[mi] << 8));
        float4 x = src[lane];
        float ss = x.x * x.x + x.y * x.y + x.z * x.z + x.w * x.w;
        #pragma unroll
        for (int off = 32; off >= 1; off >>= 1) ss += __shfl_xor(ss, off, 64);
        float inv = 1.0f / fmaxf(sqrtf(ss), 1e-12f);
        ushort4 o;
        o.x = f2b(x.x * inv); o.y = f2b(x.y * inv);
        o.z = f2b(x.z * inv); o.w = f2b(x.w * inv);
        ((ushort4*)&rows[mi * 256])[lane] = o;
    }
    __syncthreads();
    for (int pr = t; pr < M * M; pr += 256) {
        int i = pr / M, j = pr - i * M;
        if (i == j) continue;
        const uint4* ap = (const uint4*)&rows[i * 256];
        const uint4* bp = (const uint4*)&rows[j * 256];
        float s = 0.f;
        #pragma unroll 4
        for (int k = 0; k < 32; ++k) {
            uint4 a = ap[k], bb = bp[k];
            s += blo(a.x) * blo(bb.x) + bhi(a.x) * bhi(bb.x);
            s += blo(a.y) * blo(bb.y) + bhi(a.y) * bhi(bb.y);
            s += blo(a.z) * blo(bb.z) + bhi(a.z) * bhi(bb.z);
            s += blo(a.w) * blo(bb.w) + bhi(a.w) * bhi(bb.w);
        }
        atomicMin(&hp_loc[i], fkey(s));
    }
    __syncthreads();
    for (int s = t; s < M; s += 256) {
        unsigned int key = hp_loc[s];
        hp_out[list[s]] = (key == 0xFFFFFFFFu) ? BIGF : funkey(key);
    }
}

// ---------------------------------------------------------------------------
// Kernel 2: persistent MFMA pass, 16x16x32 (R8-proven conflict-free LDS
// family), wave tile 64x64 (mt=4 x nt=4: 0.5 ds_reads per MFMA), 2 blocks/CU.
// Block = 256 thr (4 waves = 4 col groups), tile 64 rows x 2048 cols.
// A (64x256, 32 KB) staged once; B 16 KB/step double-buffered; 64 steps.
// Grid = 128 strips x 4 splits = 512 blocks (2/CU: barrier stalls of one
// block overlap the other's MFMA). Partials: p[slot*N + row], 16 slots.
// ---------------------------------------------------------------------------
__global__ __launch_bounds__(256, 2) void k_pass2(
    const unsigned short* __restrict__ normed, const int* __restrict__ pids,
    const int* __restrict__ gpid, const float* __restrict__ hp,
    float* __restrict__ p_hn, float* __restrict__ p_mb, int N)
{
    __shared__ unsigned short As[64 * 256];      // 32 KB
    __shared__ unsigned short Bs[2][256 * 32];   // 2 x 16 KB
    __shared__ int pid_s[64];
    __shared__ float hp_s[64];

    const int t = threadIdx.x;
    const int lane = t & 63;
    const int wc = t >> 6;                  // 4 col groups
    const int quad = lane >> 4, l16 = lane & 15;
    const int strip = blockIdx.x >> 2;      // 128 strips of 64 rows
    const int split = blockIdx.x & 3;
    const int rbase = strip * 64;
    const int cstart = split * (N >> 2);    // colspan 2048

    if (t < 64) { pid_s[t] = pids[rbase + t]; hp_s[t] = hp[rbase + t]; }

    // ---- A prologue: 2048 chunks; C = i*256+t -> kb=C>>8, row, pos ----
    // stored chunk pos holds global chunk c = pos ^ ((row>>1)&3)
    #pragma unroll
    for (int i = 0; i < 8; ++i) {
        int C = i * 256 + t;
        int kb = C >> 8, rem = C & 255, row = rem >> 2, pos = rem & 3;
        int c = pos ^ ((row >> 1) & 3);
        async16(normed + ((size_t)(rbase + row) << 8) + kb * 32 + c * 8,
                &As[C * 8]);
    }
    // ---- B staging bases: chunk C = i*256+t -> col = i*64+(t>>2), pos=t&3
    const int bcol[4] = { 0 * 64 + (t >> 2), 1 * 64 + (t >> 2),
                          2 * 64 + (t >> 2), 3 * 64 + (t >> 2) };
    const unsigned short* gB[4];
    #pragma unroll
    for (int i = 0; i < 4; ++i) {
        int c = (t & 3) ^ ((bcol[i] >> 1) & 3);
        gB[i] = normed + ((size_t)(cstart + bcol[i]) << 8) + c * 8;
    }
    // B step-0 prefetch (ti=0, kb=0)
    #pragma unroll
    for (int i = 0; i < 4; ++i)
        async16(gB[i], &Bs[0][(i * 256 + t) * 8]);

    __syncthreads();   // drain A + B0; pid_s/hp_s visible

    // register caches: block-local rows rl = mt*16 + quad*4 + r
    int pid_c[4][4]; float hp_c[4][4];
    float hnall[4][4], mbel[4][4];
    f32x4 acc[4][4];
    #pragma unroll
    for (int mt = 0; mt < 4; ++mt)
        #pragma unroll
        for (int r = 0; r < 4; ++r) {
            int rl = mt * 16 + quad * 4 + r;
            pid_c[mt][r] = pid_s[rl];
            hp_c[mt][r] = hp_s[rl];
            hnall[mt][r] = -BIGF;
            mbel[mt][r] = -BIGF;
        }
    #pragma unroll
    for (int mt = 0; mt < 4; ++mt)
        #pragma unroll
        for (int nt = 0; nt < 4; ++nt)
            acc[mt][nt] = (f32x4){0.f, 0.f, 0.f, 0.f};

    const int sw = (l16 >> 1) & 3;
    const int aoff = l16 * 32 + (quad ^ sw) * 8;     // + mt*512 (+kb*2048)
    int gp[4];

    for (int s = 0; s < 64; ++s) {
        const int ti = s >> 3, kb = s & 7, buf = s & 1;
        if (s < 63) {
            int s1 = s + 1;
            size_t off = ((size_t)(s1 >> 3) << 16) + (size_t)(s1 & 7) * 32;
            #pragma unroll
            for (int i = 0; i < 4; ++i)
                async16(gB[i] + off, &Bs[buf ^ 1][(i * 256 + t) * 8]);
        }
        if (kb == 0) {
            int cb = cstart + ti * 256 + wc * 64;
            #pragma unroll
            for (int nt = 0; nt < 4; ++nt) gp[nt] = gpid[cb + nt * 16 + l16];
        }
        short8 af[4], bf[4];
        #pragma unroll
        for (int mt = 0; mt < 4; ++mt)
            af[mt] = *reinterpret_cast<const short8*>(
                &As[kb * 2048 + mt * 512 + aoff]);
        #pragma unroll
        for (int nt = 0; nt < 4; ++nt)
            bf[nt] = *reinterpret_cast<const short8*>(
                &Bs[buf][wc * 2048 + nt * 512 + aoff]);
        #pragma unroll
        for (int mt = 0; mt < 4; ++mt)
            #pragma unroll
            for (int nt = 0; nt < 4; ++nt)
                acc[mt][nt] = __builtin_amdgcn_mfma_f32_16x16x32_bf16(
                    af[mt], bf[nt], acc[mt][nt], 0, 0, 0);
        if (kb == 7) {
            // per-tile epilogue (VALU; co-schedules with other block's MFMA)
            #pragma unroll
            for (int mt = 0; mt < 4; ++mt)
                #pragma unroll
                for (int r = 0; r < 4; ++r) {
                    int prow = pid_c[mt][r];
                    float hprow = hp_c[mt][r];
                    #pragma unroll
                    for (int nt = 0; nt < 4; ++nt) {
                        float sv = acc[mt][nt][r];
                        float tt = (prow != gp[nt]) ? sv : -BIGF;
                        hnall[mt][r] = fmaxf(hnall[mt][r], tt);
                        float u = (tt < hprow) ? tt : -BIGF;
                        mbel[mt][r] = fmaxf(mbel[mt][r], u);
                        acc[mt][nt][r] = 0.f;
                    }
                }
        }
        __syncthreads();
    }

    // block epilogue: reduce across the 16 col-lanes, store one partial/row
    #pragma unroll
    for (int mt = 0; mt < 4; ++mt)
        #pragma unroll
        for (int r = 0; r < 4; ++r) {
            float v1 = hnall[mt][r], v2 = mbel[mt][r];
            #pragma unroll
            for (int off = 8; off >= 1; off >>= 1) {
                v1 = fmaxf(v1, __shfl_xor(v1, off, 64));
                v2 = fmaxf(v2, __shfl_xor(v2, off, 64));
            }
            if (l16 == 0) {
                int row = rbase + mt * 16 + quad * 4 + r;
                int slot = split * 4 + wc;
                p_hn[(size_t)slot * N + row] = v1;
                p_mb[(size_t)slot * N + row] = v2;
            }
        }
}

// ---------------------------------------------------------------------------
// Kernel 3: per-row loss + grid reduce + fused final (last-block pattern).
// hn = (mbel > hp - margin) ? mbel : hn_all   (hn_cand == hn_all identity)
// ---------------------------------------------------------------------------
__global__ __launch_bounds__(256) void k_rowloss(
    const float* __restrict__ hp, const float* __restrict__ p_hn,
    const float* __restrict__ p_mb, const int* __restrict__ labels,
    float* __restrict__ gred, int* __restrict__ done,
    float* __restrict__ out, int N)
{
    int i = blockIdx.x * 256 + threadIdx.x;
    float hn_all = -BIGF, mb = -BIGF;
    #pragma unroll
    for (int s = 0; s < NSLOT; ++s) {
        hn_all = fmaxf(hn_all, p_hn[(size_t)s * N + i]);
        mb = fmaxf(mb, p_mb[(size_t)s * N + i]);
    }
    float hpv = hp[i];
    bool valid = (labels[i] == 1) && (hpv < 1e8f) && (hn_all > -1e8f);
    float hn = (mb > hpv - 0.5f) ? mb : hn_all;
    float base = fmaxf(hn - hpv + 0.5f, 0.f);
    float wgt = (hpv < 0.6f || hn > 0.3f) ? 2.f : 1.f;
    float loss = base * wgt + 0.5f * (1.f - hpv) + 0.5f * fmaxf(hn + 0.2f, 0.f);
    float lsum = valid ? loss : 0.f;
    float lcnt = valid ? 1.f : 0.f;
    #pragma unroll
    for (int off = 32; off >= 1; off >>= 1) {
        lsum += __shfl_xor(lsum, off, 64);
        lcnt += __shfl_xor(lcnt, off, 64);
    }
    __shared__ float rs[4], rc[4];
    int wv = threadIdx.x >> 6, lane = threadIdx.x & 63;
    if (lane == 0) { rs[wv] = lsum; rc[wv] = lcnt; }
    __syncthreads();
    if (threadIdx.x == 0) {
        atomicAdd(&gred[0], rs[0] + rs[1] + rs[2] + rs[3]);
        atomicAdd(&gred[1], rc[0] + rc[1] + rc[2] + rc[3]);
        __threadfence();
        int old = atomicAdd(done, 1);
        if (old == (int)gridDim.x - 1) {
            float S = atomicAdd(&gred[0], 0.f);
            float C = atomicAdd(&gred[1], 0.f);
            out[0] = (C > 0.f) ? S / fmaxf(C, 1.f) : 0.f;
        }
    }
}

extern "C" void kernel_launch(void* const* d_in, const int* in_sizes, int n_in,
                              void* d_out, int out_size, void* d_ws, size_t ws_size,
                              hipStream_t stream)
{
    const float* emb = (const float*)d_in[0];
    const int* labels = (const int*)d_in[1];
    const int* pids = (const int*)d_in[2];
    float* out = (float*)d_out;
    int N = in_sizes[1];          // 8192

    char* ws = (char*)d_ws;
    unsigned short* normed = (unsigned short*)ws;  ws += (size_t)N * 256 * 2;  // 4 MB
    int* gpid = (int*)ws;                          ws += (size_t)N * 4;
    float* hp = (float*)ws;                        ws += (size_t)N * 4;
    float* p_hn = (float*)ws;                      ws += (size_t)N * NSLOT * 4;
    float* p_mb = (float*)ws;                      ws += (size_t)N * NSLOT * 4;
    float* gred = (float*)ws;                      ws += 2 * 4;
    int* done = (int*)ws;                          ws += 4;

    k_prep<<<N / 4 + 256, 256, 0, stream>>>(emb, labels, pids, normed, gpid,
                                            hp, gred, done, N);
    k_pass2<<<(N / 64) * 4, 256, 0, stream>>>(normed, pids, gpid, hp,
                                              p_hn, p_mb, N);
    k_rowloss<<<N / 256, 256, 0, stream>>>(hp, p_hn, p_mb, labels,
                                           gred, done, out, N);
}